// Round 6
// baseline (1216.417 us; speedup 1.0000x reference)
//
#include <hip/hip_runtime.h>

#define CH 128

typedef __attribute__((ext_vector_type(8))) short short8;
typedef __attribute__((ext_vector_type(4))) float floatx4;

__device__ __forceinline__ float bf2f(unsigned short u) {
    union { unsigned int i; float f; } v; v.i = ((unsigned int)u) << 16; return v.f;
}
__device__ __forceinline__ unsigned short f2bf(float f) {
    union { float f; unsigned int i; } v; v.f = f;
    unsigned int r = v.i + 0x7FFF + ((v.i >> 16) & 1);  // RNE
    return (unsigned short)(r >> 16);
}

// ---------------- utility kernels ----------------

__global__ __launch_bounds__(256) void k_zero_i(int* __restrict__ p, int n) {
    int i = blockIdx.x * 256 + threadIdx.x;
    if (i < n) p[i] = 0;
}

__global__ __launch_bounds__(256) void k_copy16(const int4* __restrict__ s, int4* __restrict__ d, int n16) {
    int i = blockIdx.x * 256 + threadIdx.x;
    if (i < n16) d[i] = s[i];
}

// all 20 weight mats (8 Ws, 6 Wh, 6 Wl) f32 (k,n) -> one bf16 arena (n,k)
__global__ __launch_bounds__(256) void k_wt_all(const float* __restrict__ Ws,
                                                const float* __restrict__ Wh,
                                                const float* __restrict__ Wl,
                                                unsigned short* __restrict__ WT) {
    int i = blockIdx.x * 256 + threadIdx.x;
    if (i >= (20 << 14)) return;
    int mat = i >> 14, rem = i & 16383;
    int k = rem >> 7, n = rem & 127;
    float w;
    if (mat < 8)       w = Ws[(mat << 14) + rem];
    else if (mat < 14) w = Wh[((mat - 8) << 14) + rem];
    else               w = Wl[((mat - 14) << 14) + rem];
    WT[(mat << 14) + (n << 7) + k] = f2bf(w);
}

// ---------------- CSR build: unified per-rank matrices ----------------
// Row space: 4 ranks concatenated (260K rows). Each rank's matrix merges
// adj + h2l + l2h with cols offset into the rank's unified y-arena.

struct Segs {
    const int*   rowsrc[10];
    const int*   colsrc[10];
    const float* valsrc[10];
    int nnz[10];
    int colOff[10];
    int rowBase[10];   // rank row base in cnt/rowptr space
    int rankId[10];
    int histStart[10]; // block starts for k_hist_all
    int fillStart[10]; // block starts for k_fillA (multiples of 8)
};

struct RankP {
    int rowBase[4];
    int sh[4];      // rows-per-bucket = 1<<sh  (sh <= 14)
    int nbuck[4];   // <= 16
    int N[4];
};

__device__ __forceinline__ int seg_hist(const Segs& sg, int blk) {
    int s = 0;
    for (int k = 1; k < 10; ++k) if (blk >= sg.histStart[k]) s = k;
    return s;
}
__device__ __forceinline__ int seg_fill(const Segs& sg, int blk) {
    int s = 0;
    for (int k = 1; k < 10; ++k) if (blk >= sg.fillStart[k]) s = k;
    return s;
}

__global__ __launch_bounds__(256) void k_hist_all(Segs sg, int* __restrict__ cnt) {
    int s = seg_hist(sg, blockIdx.x);
    int i = (blockIdx.x - sg.histStart[s]) * 256 + threadIdx.x;
    if (i < sg.nnz[s]) atomicAdd(&cnt[sg.rowBase[s] + sg.rowsrc[s][i]], 1);
}

// hierarchical exclusive scan over cnt (totalRows ~260K, nb blocks of 4096)
__global__ __launch_bounds__(256) void k_scan_partial(const int* __restrict__ cnt, int* __restrict__ part, int n) {
    __shared__ int swt[4];
    int t = threadIdx.x, lane = t & 63, w = t >> 6;
    int base = blockIdx.x * 4096 + t * 16;
    int s = 0;
#pragma unroll
    for (int k = 0; k < 16; ++k) {
        int i = base + k;
        if (i < n) s += cnt[i];
    }
    for (int off = 1; off < 64; off <<= 1) s += __shfl_xor(s, off, 64);
    if (lane == 0) swt[w] = s;
    __syncthreads();
    if (t == 0) part[blockIdx.x] = swt[0] + swt[1] + swt[2] + swt[3];
}

__global__ __launch_bounds__(256) void k_scan_part(int* __restrict__ part, int nb, int* __restrict__ totalOut) {
    __shared__ int swt[4];
    __shared__ int scarry;
    int t = threadIdx.x, lane = t & 63, w = t >> 6;
    if (t == 0) scarry = 0;
    __syncthreads();
    for (int base = 0; base < nb; base += 256) {
        int i = base + t;
        int v = (i < nb) ? part[i] : 0;
        int incl = v;
        for (int off = 1; off < 64; off <<= 1) {
            int u = __shfl_up(incl, off, 64);
            if (lane >= off) incl += u;
        }
        if (lane == 63) swt[w] = incl;
        __syncthreads();
        int waveoff = 0;
        for (int k = 0; k < w; ++k) waveoff += swt[k];
        int running = scarry;
        if (i < nb) part[i] = running + waveoff + incl - v;
        __syncthreads();
        if (t == 255) scarry = running + waveoff + incl;
        __syncthreads();
    }
    if (t == 0) *totalOut = scarry;
}

__global__ __launch_bounds__(256) void k_scan_final(const int* __restrict__ cnt, const int* __restrict__ part,
                                                    int* __restrict__ rowptr, int* __restrict__ cursor, int n) {
    __shared__ int swt[4];
    int t = threadIdx.x, lane = t & 63, w = t >> 6;
    int base = blockIdx.x * 4096 + t * 16;
    int v[16];
    int s = 0;
#pragma unroll
    for (int k = 0; k < 16; ++k) {
        int i = base + k;
        v[k] = (i < n) ? cnt[i] : 0;
        s += v[k];
    }
    int incl = s;
    for (int off = 1; off < 64; off <<= 1) {
        int u = __shfl_up(incl, off, 64);
        if (lane >= off) incl += u;
    }
    if (lane == 63) swt[w] = incl;
    __syncthreads();
    int waveoff = 0;
    for (int k = 0; k < w; ++k) waveoff += swt[k];
    int run = part[blockIdx.x] + waveoff + incl - s;
#pragma unroll
    for (int k = 0; k < 16; ++k) {
        int i = base + k;
        if (i < n) { rowptr[i] = run; cursor[i] = run; }
        run += v[k];
    }
}

// cursorA[r*16+b] = rowptr[rowBase_r + min(b<<sh, N_r)]
__global__ __launch_bounds__(64) void k_initcur(RankP rp, const int* __restrict__ rowptr,
                                                int* __restrict__ cursorA) {
    int t = threadIdx.x;
    int r = t >> 4, b = t & 15;
    int ri = b << rp.sh[r];
    if (ri > rp.N[r]) ri = rp.N[r];
    cursorA[t] = rowptr[rp.rowBase[r] + ri];
}

// Phase A: bin edges into bucket regions of the stage arena (XCD-affine via
// blockIdx%8), LDS-aggregated so appends are bulk + coalesced.
// stage record: (col | rowlocal<<18, val)   col<2^18, rowlocal<2^14
#define FILLA_CAP 2048

__global__ __launch_bounds__(256) void k_fillA(Segs sg, RankP rp, int* __restrict__ cursorA,
                                               int2* __restrict__ stage) {
    __shared__ int lcnt[2];
    __shared__ int sbase[2];
    __shared__ int2 lbuf[2][FILLA_CAP];
    int s = seg_fill(sg, blockIdx.x);
    int local = blockIdx.x - sg.fillStart[s];
    int chunk = local >> 3;
    int q = local & 7;                 // == blockIdx.x % 8 (starts are %8==0)
    int rank = sg.rankId[s];
    int sh = rp.sh[rank];
    int colOff = sg.colOff[s];
    int nnz = sg.nnz[s];
    int t = threadIdx.x;
    if (t < 2) lcnt[t] = 0;
    __syncthreads();
    int base = chunk * 4096;
#pragma unroll 4
    for (int k = 0; k < 16; ++k) {
        int i = base + k * 256 + t;
        if (i >= nnz) continue;
        int row = sg.rowsrc[s][i];
        int b = row >> sh;
        if ((b & 7) != q) continue;
        int which = b >> 3;
        int packed = (sg.colsrc[s][i] + colOff) | ((row & ((1 << sh) - 1)) << 18);
        int vi = __float_as_int(sg.valsrc[s][i]);
        int idx = atomicAdd(&lcnt[which], 1);
        if (idx < FILLA_CAP) lbuf[which][idx] = make_int2(packed, vi);
        else {  // overflow slow path (statistically never at these densities)
            int p = atomicAdd(&cursorA[rank * 16 + b], 1);
            stage[p] = make_int2(packed, vi);
        }
    }
    __syncthreads();
    if (t == 0) {
        int n0 = lcnt[0]; if (n0 > FILLA_CAP) n0 = FILLA_CAP;
        int n1 = lcnt[1]; if (n1 > FILLA_CAP) n1 = FILLA_CAP;
        sbase[0] = atomicAdd(&cursorA[rank * 16 + q], n0);
        sbase[1] = atomicAdd(&cursorA[rank * 16 + q + 8], n1);
    }
    __syncthreads();
    for (int which = 0; which < 2; ++which) {
        int n = lcnt[which]; if (n > FILLA_CAP) n = FILLA_CAP;
        int b0 = sbase[which];
        for (int i = t; i < n; i += 256) stage[b0 + i] = lbuf[which][i];
    }
}

// Phase B: within each bucket region (XCD-L2-sized, XCD-affine), scatter to
// final CSR positions via row cursors.
__global__ __launch_bounds__(256) void k_fillB(RankP rp, const int* __restrict__ rowptr,
                                               const int2* __restrict__ stage,
                                               int* __restrict__ cursor,
                                               int2* __restrict__ eArena) {
    int q = blockIdx.x & 7;
    int k = blockIdx.x >> 3;
    int K = gridDim.x >> 3;
    int t = threadIdx.x;
    for (int r = 0; r < 4; ++r) {
        int sh = rp.sh[r], N = rp.N[r], rb = rp.rowBase[r];
        for (int b = q; b < rp.nbuck[r]; b += 8) {
            int r0 = b << sh;
            int r1 = (b + 1) << sh; if (r1 > N) r1 = N;
            int g0 = rowptr[rb + r0];
            int g1 = rowptr[rb + r1];
            for (int idx = g0 + k * 256 + t; idx < g1; idx += K * 256) {
                int2 e = stage[idx];
                int col = e.x & 0x3FFFF;
                int row = r0 + (((unsigned)e.x) >> 18);
                int p = atomicAdd(&cursor[rb + row], 1);
                eArena[p] = make_int2(col, e.y);
            }
        }
    }
}

// ---------------- GEMM: up to 3 sub-GEMMs per dispatch ----------------

struct G3 {
    const void* A[3];
    const unsigned short* Bt[3];
    unsigned short* Y[3];
    int M[3];
    int blk0[3];
    int nsub;
    int isF32;
};

__device__ __forceinline__ int lds_idx(int r, int koff) {
    return (r << 7) + ((((koff >> 3) ^ (r & 15))) << 3);
}

__device__ __forceinline__ void gemm_core(const unsigned short* sA, const unsigned short* sB,
                                          unsigned short* __restrict__ Y, int M, int row0, int t) {
    const int wave = t >> 6;
    const int lane = t & 63;
    const int quad = lane >> 4;
    const int l16  = lane & 15;
    const int rbase = wave * 32;

    floatx4 acc[2][8];
    for (int i = 0; i < 2; ++i)
        for (int j = 0; j < 8; ++j) acc[i][j] = (floatx4){0.f, 0.f, 0.f, 0.f};

    for (int kk = 0; kk < 4; ++kk) {
        int ko = kk * 32 + quad * 8;
        short8 a0 = *(const short8*)(&sA[lds_idx(rbase + l16, ko)]);
        short8 a1 = *(const short8*)(&sA[lds_idx(rbase + 16 + l16, ko)]);
        for (int j = 0; j < 8; ++j) {
            short8 b = *(const short8*)(&sB[lds_idx(j * 16 + l16, ko)]);
            acc[0][j] = __builtin_amdgcn_mfma_f32_16x16x32_bf16(a0, b, acc[0][j], 0, 0, 0);
            acc[1][j] = __builtin_amdgcn_mfma_f32_16x16x32_bf16(a1, b, acc[1][j], 0, 0, 0);
        }
    }

    for (int i = 0; i < 2; ++i) {
        int rg0 = row0 + rbase + i * 16 + quad * 4;
        for (int reg = 0; reg < 4; ++reg) {
            int rg = rg0 + reg;
            if (rg >= M) continue;
            unsigned short* yr = Y + (size_t)rg * CH;
            for (int j = 0; j < 8; ++j)
                yr[j * 16 + l16] = f2bf(acc[i][j][reg]);
        }
    }
}

__global__ __launch_bounds__(256) void k_gemm3(G3 g) {
    __shared__ __align__(16) unsigned short sA[128 * 128];
    __shared__ __align__(16) unsigned short sB[128 * 128];
    const int t = threadIdx.x;
    int sub = 0;
    if (g.nsub > 1 && (int)blockIdx.x >= g.blk0[1]) sub = 1;
    if (g.nsub > 2 && (int)blockIdx.x >= g.blk0[2]) sub = 2;
    const int row0 = (blockIdx.x - g.blk0[sub]) * 128;
    const int M = g.M[sub];
    const unsigned short* Bt = g.Bt[sub];
    unsigned short* Y = g.Y[sub];

    if (g.isF32) {
        const float* A = (const float*)g.A[sub];
        for (int it = 0; it < 8; ++it) {
            int chunk = it * 256 + t;
            int r = chunk >> 4;
            int cidx = chunk & 15;
            int coff = cidx << 3;
            int sidx = (r << 7) + (((cidx ^ (r & 15))) << 3);
            *(float4*)(&sB[sidx]) = *(const float4*)(Bt + (r << 7) + coff);
            int gr = row0 + r;
            unsigned short us[8];
            if (gr < M) {
                const float* ar = A + (size_t)gr * CH + coff;
                float4 f0 = *(const float4*)ar;
                float4 f1 = *(const float4*)(ar + 4);
                us[0] = f2bf(f0.x); us[1] = f2bf(f0.y); us[2] = f2bf(f0.z); us[3] = f2bf(f0.w);
                us[4] = f2bf(f1.x); us[5] = f2bf(f1.y); us[6] = f2bf(f1.z); us[7] = f2bf(f1.w);
            } else {
                for (int k = 0; k < 8; ++k) us[k] = 0;
            }
            *(float4*)(&sA[sidx]) = *(const float4*)us;
        }
    } else {
        const unsigned short* A = (const unsigned short*)g.A[sub];
        for (int it = 0; it < 8; ++it) {
            int chunk = it * 256 + t;
            int r = chunk >> 4;
            int cidx = chunk & 15;
            int coff = cidx << 3;
            int sidx = (r << 7) + (((cidx ^ (r & 15))) << 3);
            *(float4*)(&sB[sidx]) = *(const float4*)(Bt + (r << 7) + coff);
            int gr = row0 + r;
            float4 av = make_float4(0.f, 0.f, 0.f, 0.f);
            if (gr < M) av = *(const float4*)(A + (size_t)gr * CH + coff);
            *(float4*)(&sA[sidx]) = av;
        }
    }
    __syncthreads();
    gemm_core(sA, sB, Y, M, row0, t);
}

// ---------------- unified gather + sigmoid ----------------
// one wave per row; single CSR merging adj/h2l/l2h (cols index unified yU).

__global__ __launch_bounds__(256) void k_gather(const int* __restrict__ rp,
                                                const int2* __restrict__ eg,
                                                const unsigned short* __restrict__ yU,
                                                unsigned short* __restrict__ xout, int M) {
    int wrow = blockIdx.x * 4 + (threadIdx.x >> 6);
    if (wrow >= M) return;
    int lane = threadIdx.x & 63;
    int coff = lane * 2;
    int jb = __builtin_amdgcn_readfirstlane(rp[wrow]);
    int je = __builtin_amdgcn_readfirstlane(rp[wrow + 1]);
    float a0 = 0.f, a1 = 0.f;
    int j = jb;
    for (; j + 8 <= je; j += 8) {
        int2 e0 = eg[j],     e1 = eg[j + 1], e2 = eg[j + 2], e3 = eg[j + 3];
        int2 e4 = eg[j + 4], e5 = eg[j + 5], e6 = eg[j + 6], e7 = eg[j + 7];
        unsigned int u0 = *(const unsigned int*)(yU + (((size_t)(unsigned)e0.x) << 7) + coff);
        unsigned int u1 = *(const unsigned int*)(yU + (((size_t)(unsigned)e1.x) << 7) + coff);
        unsigned int u2 = *(const unsigned int*)(yU + (((size_t)(unsigned)e2.x) << 7) + coff);
        unsigned int u3 = *(const unsigned int*)(yU + (((size_t)(unsigned)e3.x) << 7) + coff);
        unsigned int u4 = *(const unsigned int*)(yU + (((size_t)(unsigned)e4.x) << 7) + coff);
        unsigned int u5 = *(const unsigned int*)(yU + (((size_t)(unsigned)e5.x) << 7) + coff);
        unsigned int u6 = *(const unsigned int*)(yU + (((size_t)(unsigned)e6.x) << 7) + coff);
        unsigned int u7 = *(const unsigned int*)(yU + (((size_t)(unsigned)e7.x) << 7) + coff);
        float v0 = __int_as_float(e0.y), v1 = __int_as_float(e1.y);
        float v2 = __int_as_float(e2.y), v3 = __int_as_float(e3.y);
        float v4 = __int_as_float(e4.y), v5 = __int_as_float(e5.y);
        float v6 = __int_as_float(e6.y), v7 = __int_as_float(e7.y);
        a0 += v0 * __int_as_float(u0 << 16); a1 += v0 * __int_as_float(u0 & 0xffff0000u);
        a0 += v1 * __int_as_float(u1 << 16); a1 += v1 * __int_as_float(u1 & 0xffff0000u);
        a0 += v2 * __int_as_float(u2 << 16); a1 += v2 * __int_as_float(u2 & 0xffff0000u);
        a0 += v3 * __int_as_float(u3 << 16); a1 += v3 * __int_as_float(u3 & 0xffff0000u);
        a0 += v4 * __int_as_float(u4 << 16); a1 += v4 * __int_as_float(u4 & 0xffff0000u);
        a0 += v5 * __int_as_float(u5 << 16); a1 += v5 * __int_as_float(u5 & 0xffff0000u);
        a0 += v6 * __int_as_float(u6 << 16); a1 += v6 * __int_as_float(u6 & 0xffff0000u);
        a0 += v7 * __int_as_float(u7 << 16); a1 += v7 * __int_as_float(u7 & 0xffff0000u);
    }
    for (; j < je; ++j) {
        int2 e = eg[j];
        unsigned int u = *(const unsigned int*)(yU + (((size_t)(unsigned)e.x) << 7) + coff);
        float v = __int_as_float(e.y);
        a0 += v * __int_as_float(u << 16);
        a1 += v * __int_as_float(u & 0xffff0000u);
    }
    float s0 = 1.0f / (1.0f + __expf(-a0));
    float s1 = 1.0f / (1.0f + __expf(-a1));
    ushort2 o;
    o.x = f2bf(s0);
    o.y = f2bf(s1);
    *(ushort2*)(xout + (size_t)wrow * CH + coff) = o;
}

// ---------------- output head ----------------

__global__ __launch_bounds__(128) void k_out(const unsigned short* __restrict__ x0,
                                             const float* __restrict__ Wout,
                                             const float* __restrict__ bout,
                                             float* __restrict__ out, int M) {
    __shared__ float sl[8][16];
    int rlocal = threadIdx.x >> 4;
    int o = threadIdx.x & 15;
    int rowi = blockIdx.x * 8 + rlocal;
    float acc = 0.f;
    if (rowi < M && o < 10) {
        const unsigned short* xr = x0 + (size_t)rowi * CH;
        for (int k = 0; k < CH; ++k)
            acc += bf2f(xr[k]) * Wout[k * 10 + o];
        acc += bout[o];
    }
    sl[rlocal][o] = acc;
    __syncthreads();
    if (rowi < M && o < 10) {
        float mx = -1e30f;
        for (int j = 0; j < 10; ++j) mx = fmaxf(mx, sl[rlocal][j]);
        float s = 0.f;
        for (int j = 0; j < 10; ++j) s += __expf(sl[rlocal][j] - mx);
        out[rowi * 10 + o] = __expf(sl[rlocal][o] - mx) / s;
    }
}

// ---------------- launch ----------------

extern "C" void kernel_launch(void* const* d_in, const int* in_sizes, int n_in,
                              void* d_out, int out_size, void* d_ws, size_t ws_size,
                              hipStream_t stream) {
    const float* xin[4];
    for (int r = 0; r < 4; ++r) xin[r] = (const float*)d_in[r];
    const int* arow[4]; const int* acol[4]; const float* aval[4];
    for (int r = 0; r < 4; ++r) {
        arow[r] = (const int*)d_in[4 + 3 * r];
        acol[r] = (const int*)d_in[5 + 3 * r];
        aval[r] = (const float*)d_in[6 + 3 * r];
    }
    const int* irow[3]; const int* icol[3]; const float* ival[3];
    for (int r = 0; r < 3; ++r) {
        irow[r] = (const int*)d_in[16 + 3 * r];
        icol[r] = (const int*)d_in[17 + 3 * r];
        ival[r] = (const float*)d_in[18 + 3 * r];
    }
    const float* W_same = (const float*)d_in[25];
    const float* W_h2l  = (const float*)d_in[26];
    const float* W_l2h  = (const float*)d_in[27];
    const float* W_out  = (const float*)d_in[28];
    const float* b_out  = (const float*)d_in[29];

    int Nr[4], adjnnz[4], incnnz[3];
    for (int r = 0; r < 4; ++r) { Nr[r] = in_sizes[r] / CH; adjnnz[r] = in_sizes[4 + 3 * r]; }
    for (int r = 0; r < 3; ++r) incnnz[r] = in_sizes[16 + 3 * r];
    size_t totalN = (size_t)Nr[0] + Nr[1] + Nr[2] + Nr[3];
    size_t totAdj = 0; for (int r = 0; r < 4; ++r) totAdj += adjnnz[r];
    size_t totInc = 0; for (int r = 0; r < 3; ++r) totInc += incnnz[r];
    size_t totEdges = totAdj + 2 * totInc;

    // unified y-arena geometry per rank
    int yRows[4], offH[4], offL[4];
    int yRowsMax = 0;
    for (int r = 0; r < 4; ++r) {
        offH[r] = Nr[r];
        offL[r] = Nr[r] + (r < 3 ? Nr[r + 1] : 0);
        yRows[r] = offL[r] + (r > 0 ? Nr[r - 1] : 0);
        if (yRows[r] > yRowsMax) yRowsMax = yRows[r];
    }
    int Nmax = 0;
    for (int r = 0; r < 4; ++r) if (Nr[r] > Nmax) Nmax = Nr[r];

    // rank params
    RankP rp;
    int totalRows = 0;
    for (int r = 0; r < 4; ++r) {
        rp.rowBase[r] = totalRows; totalRows += Nr[r];
        int sh = 0;
        while (((Nr[r] + (1 << sh) - 1) >> sh) > 16) sh++;
        rp.sh[r] = sh;
        rp.nbuck[r] = (Nr[r] + (1 << sh) - 1) >> sh;
        rp.N[r] = Nr[r];
    }
    int nb = (totalRows + 4095) / 4096;

    // ---- workspace (~187 MB) ----
    char* ws = (char*)d_ws;
    size_t off = 0;
    auto take = [&](size_t bytes) { char* p = ws + off; off += (bytes + 255) & ~(size_t)255; return p; };
    unsigned short* xbuf  = (unsigned short*)take(totalN * CH * 2);
    unsigned short* xsave = (unsigned short*)take((size_t)Nmax * CH * 2);
    unsigned short* yU    = (unsigned short*)take((size_t)yRowsMax * CH * 2);  // also stage arena overlay
    unsigned short* WT    = (unsigned short*)take((size_t)20 * 16384 * 2);
    int*  cntG    = (int*)take((size_t)totalRows * 4);
    int*  rowptrG = (int*)take(((size_t)totalRows + 1) * 4);
    int*  part    = (int*)take((size_t)nb * 4);
    int*  cursorA = (int*)take(64 * 4);
    int2* eArena  = (int2*)take(totEdges * 8);
    (void)ws_size;

    unsigned short* WsT = WT;
    unsigned short* WhT = WT + ((size_t)8 << 14);
    unsigned short* WlT = WT + ((size_t)14 << 14);

    unsigned short* x[4];
    {
        size_t o = 0;
        for (int r = 0; r < 4; ++r) { x[r] = xbuf + o; o += (size_t)Nr[r] * CH; }
    }
    int2* stage = (int2*)yU;  // fill runs before any GEMM writes yU

    // ---- segment table: adj0-3, h2l(s=0..2), l2h(s=0..2) ----
    Segs sg;
    int hblk = 0, fblk = 0;
    auto addseg = [&](int idx, const int* rs, const int* cs, const float* vs, int nnz,
                      int colOff, int rank) {
        sg.rowsrc[idx] = rs; sg.colsrc[idx] = cs; sg.valsrc[idx] = vs;
        sg.nnz[idx] = nnz; sg.colOff[idx] = colOff;
        sg.rowBase[idx] = rp.rowBase[rank]; sg.rankId[idx] = rank;
        sg.histStart[idx] = hblk; hblk += (nnz + 255) / 256;
        sg.fillStart[idx] = fblk; fblk += 8 * ((nnz + 4095) / 4096);
    };
    for (int r = 0; r < 4; ++r) addseg(r, arow[r], acol[r], aval[r], adjnnz[r], 0, r);
    for (int s = 0; s < 3; ++s) addseg(4 + s, irow[s], icol[s], ival[s], incnnz[s], offH[s], s);
    for (int s = 0; s < 3; ++s) addseg(7 + s, icol[s], irow[s], ival[s], incnnz[s], offL[s + 1], s + 1);

    // ---- CSR build ----
    k_zero_i<<<(totalRows + 255) / 256, 256, 0, stream>>>(cntG, totalRows);
    k_hist_all<<<hblk, 256, 0, stream>>>(sg, cntG);
    k_scan_partial<<<nb, 256, 0, stream>>>(cntG, part, totalRows);
    k_scan_part<<<1, 256, 0, stream>>>(part, nb, rowptrG + totalRows);
    k_scan_final<<<nb, 256, 0, stream>>>(cntG, part, rowptrG, cntG, totalRows);
    k_initcur<<<1, 64, 0, stream>>>(rp, rowptrG, cursorA);
    k_fillA<<<fblk, 256, 0, stream>>>(sg, rp, cursorA, stage);
    k_fillB<<<512, 256, 0, stream>>>(rp, rowptrG, stage, cntG, eArena);

    // ---- weights ----
    k_wt_all<<<(20 * 16384 + 255) / 256, 256, 0, stream>>>(W_same, W_h2l, W_l2h, WT);

    // ---- layers ----
    for (int l = 0; l < 2; ++l) {
        for (int r = 0; r < 4; ++r) {
            int M = Nr[r];
            G3 g;
            g.isF32 = (l == 0);
            int ns = 0, blk = 0;
            // S
            g.A[ns] = (l == 0) ? (const void*)xin[r] : (const void*)x[r];
            g.Bt[ns] = WsT + (((size_t)(l * 4 + r)) << 14);
            g.Y[ns] = yU; g.M[ns] = M; g.blk0[ns] = blk;
            blk += (M + 127) / 128; ++ns;
            // H (reads x_{r+1}, not yet overwritten this layer)
            if (r < 3) {
                int Ms = Nr[r + 1];
                g.A[ns] = (l == 0) ? (const void*)xin[r + 1] : (const void*)x[r + 1];
                g.Bt[ns] = WhT + (((size_t)(l * 3 + r)) << 14);
                g.Y[ns] = yU + (size_t)offH[r] * CH; g.M[ns] = Ms; g.blk0[ns] = blk;
                blk += (Ms + 127) / 128; ++ns;
            }
            // L (reads old x_{r-1}: pristine xin for l=0, xsave for l=1)
            if (r > 0) {
                int Ms = Nr[r - 1];
                g.A[ns] = (l == 0) ? (const void*)xin[r - 1] : (const void*)xsave;
                g.Bt[ns] = WlT + (((size_t)(l * 3 + r - 1)) << 14);
                g.Y[ns] = yU + (size_t)offL[r] * CH; g.M[ns] = Ms; g.blk0[ns] = blk;
                blk += (Ms + 127) / 128; ++ns;
            }
            g.nsub = ns;
            k_gemm3<<<blk, 256, 0, stream>>>(g);

            // preserve old x_r for next rank's l2h (layer 1 only)
            if (l == 1 && r < 3) {
                int n16 = M * 16;
                k_copy16<<<(n16 + 255) / 256, 256, 0, stream>>>((const int4*)x[r], (int4*)xsave, n16);
            }
            k_gather<<<(M + 3) / 4, 256, 0, stream>>>(rowptrG + rp.rowBase[r], eArena, yU, x[r], M);
        }
    }

    k_out<<<(Nr[0] + 7) / 8, 128, 0, stream>>>(x[0], W_out, b_out, (float*)d_out, Nr[0]);
}